// Round 1
// baseline (8674.336 us; speedup 1.0000x reference)
//
#include <hip/hip_runtime.h>
#include <hip/hip_bf16.h>

// ---------------------------------------------------------------------------
// GNN pretrain forward: h=relu(x@Wl+bl); 5x [scatter-agg -> MLP -> batchnorm]
// N=100000 nodes, E=400000 edges, DIM=256, hidden 512.
// Strategy: bf16 MFMA GEMMs (fp32 accum), fp32 atomics for segment_sum,
// 9-entry edge-embedding table, BN via column sums.
// ---------------------------------------------------------------------------

typedef __bf16 bf16x8 __attribute__((ext_vector_type(8)));
typedef float f32x4 __attribute__((ext_vector_type(4)));

#define BM 64
#define BN 64
#define BK 32

// C[M x Nc] = act(A[M x K] @ BT[Nc x K]^T + bias), A fp32 or bf16, C fp32 or bf16
template<typename AT, typename CT, int RELU>
__global__ __launch_bounds__(256)
void gemm_kernel(const void* __restrict__ Av, const __bf16* __restrict__ BT,
                 const float* __restrict__ bias, void* __restrict__ Cv,
                 int M, int K, int Nc)
{
    __shared__ __bf16 As[BM][BK];
    __shared__ __bf16 Bs[BN][BK];

    const int tid  = threadIdx.x;
    const int wave = tid >> 6;
    const int lane = tid & 63;
    const int quad = lane >> 4;
    const int l16  = lane & 15;

    const int row0 = blockIdx.x * BM;
    const int col0 = blockIdx.y * BN;

    f32x4 acc[4];
#pragma unroll
    for (int t = 0; t < 4; ++t) acc[t] = (f32x4){0.f, 0.f, 0.f, 0.f};

    // staging: 256 threads x 8 elems = 2048 = 64x32 tile
    const int srow = tid >> 2;        // 0..63
    const int scol = (tid & 3) * 8;   // 0,8,16,24

    const int a_row = row0 + srow;
    const bool a_ok = (a_row < M);
    const __bf16* Bp = BT + (size_t)(col0 + srow) * K + scol;

    for (int k0 = 0; k0 < K; k0 += BK) {
        // global loads (before barrier so they overlap prior compute)
        bf16x8 aval;
        if constexpr (sizeof(AT) == 4) {
            const float* Ap = (const float*)Av + (size_t)a_row * K + k0 + scol;
            f32x4 x0 = {0.f,0.f,0.f,0.f}, x1 = {0.f,0.f,0.f,0.f};
            if (a_ok) { x0 = *(const f32x4*)(Ap); x1 = *(const f32x4*)(Ap + 4); }
#pragma unroll
            for (int j = 0; j < 4; ++j) {
                aval[j]     = (__bf16)x0[j];
                aval[4 + j] = (__bf16)x1[j];
            }
        } else {
            const __bf16* Ap = (const __bf16*)Av + (size_t)a_row * K + k0 + scol;
            if (a_ok) aval = *(const bf16x8*)Ap;
            else {
#pragma unroll
                for (int j = 0; j < 8; ++j) aval[j] = (__bf16)0.f;
            }
        }
        bf16x8 bval = *(const bf16x8*)(Bp + k0);

        __syncthreads();  // previous iter's LDS reads done
        *(bf16x8*)&As[srow][scol] = aval;
        *(bf16x8*)&Bs[srow][scol] = bval;
        __syncthreads();

        // fragments: A[m=l16][k=quad*8+j], B^T[n=l16][k=quad*8+j]
        bf16x8 af = *(const bf16x8*)&As[wave * 16 + l16][quad * 8];
#pragma unroll
        for (int t = 0; t < 4; ++t) {
            bf16x8 bf = *(const bf16x8*)&Bs[t * 16 + l16][quad * 8];
            acc[t] = __builtin_amdgcn_mfma_f32_16x16x32_bf16(af, bf, acc[t], 0, 0, 0);
        }
    }

    // epilogue: D row = quad*4 + r (within wave's 16 rows), col = t*16 + l16
#pragma unroll
    for (int t = 0; t < 4; ++t) {
        const int col = col0 + t * 16 + l16;
        const float b = bias[col];
#pragma unroll
        for (int r = 0; r < 4; ++r) {
            const int row = row0 + wave * 16 + quad * 4 + r;
            if (row < M) {
                float v = acc[t][r] + b;
                if (RELU) v = fmaxf(v, 0.f);
                if constexpr (sizeof(CT) == 4)
                    ((float*)Cv)[(size_t)row * Nc + col] = v;
                else
                    ((__bf16*)Cv)[(size_t)row * Nc + col] = (__bf16)v;
            }
        }
    }
}

// WT[l][n][k] = (bf16) W[l][k][n]
__global__ void convert_wt_kernel(const float* __restrict__ W, __bf16* __restrict__ WT,
                                  int K, int Nc, int total)
{
    int i = blockIdx.x * 256 + threadIdx.x;
    if (i >= total) return;
    int kn = K * Nc;
    int l = i / kn;
    int rem = i - l * kn;
    int n = rem / K;
    int k = rem - n * K;
    WT[i] = (__bf16)W[(size_t)l * kn + (size_t)k * Nc + n];
}

// tab[c=bt*3+bd][256] = E1[l][bt] + E2[l][bd]; selfemb = E1[l][4]+E2[l][0]; zero sums
__global__ void build_table_kernel(const float* __restrict__ E1, const float* __restrict__ E2,
                                   int l, float* __restrict__ tab, float* __restrict__ selfemb,
                                   float* __restrict__ sums)
{
    int b = blockIdx.x;
    int t = threadIdx.x;
    const float* e1 = E1 + (size_t)l * 6 * 256;
    const float* e2 = E2 + (size_t)l * 3 * 256;
    if (b < 9) {
        tab[b * 256 + t] = e1[(b / 3) * 256 + t] + e2[(b % 3) * 256 + t];
    } else {
        selfemb[t] = e1[4 * 256 + t] + e2[0 * 256 + t];
        sums[t] = 0.f;
        sums[256 + t] = 0.f;
    }
}

// agg = h + selfemb (broadcast over rows), float4 elementwise
__global__ __launch_bounds__(256)
void init_agg_kernel(const float* __restrict__ h, const float* __restrict__ selfemb,
                     float* __restrict__ agg, int total4)
{
    int i = blockIdx.x * 256 + threadIdx.x;
    if (i >= total4) return;
    int cg = i & 63;  // 64 float4 per 256-wide row
    f32x4 s = ((const f32x4*)selfemb)[cg];
    f32x4 hv = ((const f32x4*)h)[i];
    ((f32x4*)agg)[i] = hv + s;
}

// agg[dst] += h[src] + tab[c]; 4 edges/block, 64 lanes/edge, 4 floats/lane
__global__ __launch_bounds__(256)
void scatter_kernel(const float* __restrict__ h, const int* __restrict__ ei,
                    const int* __restrict__ ea, const float* __restrict__ tab,
                    float* __restrict__ agg, int E)
{
    int e = blockIdx.x * 4 + (threadIdx.x >> 6);
    if (e >= E) return;
    int lane = threadIdx.x & 63;
    int src = ei[e];
    int dst = ei[E + e];
    int c = ea[2 * e] * 3 + ea[2 * e + 1];
    int f = lane * 4;
    f32x4 hv = *(const f32x4*)(h + (size_t)src * 256 + f);
    f32x4 tv = *(const f32x4*)(tab + c * 256 + f);
    float* d = agg + (size_t)dst * 256 + f;
    atomicAdd(d + 0, hv[0] + tv[0]);
    atomicAdd(d + 1, hv[1] + tv[1]);
    atomicAdd(d + 2, hv[2] + tv[2]);
    atomicAdd(d + 3, hv[3] + tv[3]);
}

// column sums / sumsq over rows (256 cols), one column per thread, row-chunked
__global__ __launch_bounds__(256)
void bn_stats_kernel(const float* __restrict__ out, float* __restrict__ sums,
                     int M, int rows_per_block)
{
    int col = threadIdx.x;
    int r0 = blockIdx.x * rows_per_block;
    int r1 = min(M, r0 + rows_per_block);
    float s = 0.f, ss = 0.f;
    for (int r = r0; r < r1; ++r) {
        float v = out[(size_t)r * 256 + col];
        s += v;
        ss += v * v;
    }
    atomicAdd(&sums[col], s);
    atomicAdd(&sums[256 + col], ss);
}

__global__ void bn_finalize_kernel(const float* __restrict__ sums,
                                   const float* __restrict__ gamma,
                                   const float* __restrict__ beta,
                                   int l, int M, float* __restrict__ scsh)
{
    int c = threadIdx.x;  // 256
    float inv = 1.f / (float)M;
    float mean = sums[c] * inv;
    float var = sums[256 + c] * inv - mean * mean;
    float sc = gamma[l * 256 + c] * rsqrtf(var + 1e-5f);
    scsh[c] = sc;
    scsh[256 + c] = beta[l * 256 + c] - mean * sc;
}

// h = out * scale + shift
__global__ __launch_bounds__(256)
void bn_apply_kernel(const float* __restrict__ out, const float* __restrict__ scsh,
                     float* __restrict__ h, int total4)
{
    int i = blockIdx.x * 256 + threadIdx.x;
    if (i >= total4) return;
    int cg = i & 63;
    f32x4 sc = ((const f32x4*)scsh)[cg];
    f32x4 sh = ((const f32x4*)scsh)[64 + cg];
    f32x4 v = ((const f32x4*)out)[i];
    ((f32x4*)h)[i] = v * sc + sh;
}

extern "C" void kernel_launch(void* const* d_in, const int* in_sizes, int n_in,
                              void* d_out, int out_size, void* d_ws, size_t ws_size,
                              hipStream_t stream)
{
    const float* x     = (const float*)d_in[0];
    const int*   ei    = (const int*)d_in[1];
    const int*   ea    = (const int*)d_in[2];
    const float* Wl    = (const float*)d_in[3];
    const float* bl    = (const float*)d_in[4];
    const float* W1    = (const float*)d_in[5];
    const float* b1    = (const float*)d_in[6];
    const float* W2    = (const float*)d_in[7];
    const float* b2    = (const float*)d_in[8];
    const float* E1    = (const float*)d_in[9];
    const float* E2    = (const float*)d_in[10];
    const float* gamma = (const float*)d_in[11];
    const float* beta  = (const float*)d_in[12];

    const int N = in_sizes[0] / 128;
    const int E = in_sizes[1] / 2;

    // workspace layout
    float*  h    = (float*)d_out;                    // N x 256 fp32 (also final out)
    float*  agg  = (float*)d_ws;                     // N x 256 fp32 (also gemm2 out)
    __bf16* hid  = (__bf16*)(agg + (size_t)N * 256); // N x 512 bf16
    __bf16* WlT  = hid + (size_t)N * 512;            // 256 x 128
    __bf16* W1T  = WlT + 256 * 128;                  // 5 x 512 x 256
    __bf16* W2T  = W1T + 5 * 512 * 256;              // 5 x 256 x 512
    float*  tab  = (float*)(W2T + 5 * 256 * 512);    // 9 x 256
    float*  selfemb = tab + 9 * 256;                 // 256
    float*  sums = selfemb + 256;                    // 512
    float*  scsh = sums + 512;                       // 512

    // weight conversion (transposed bf16)
    convert_wt_kernel<<<(128 * 256 + 255) / 256, 256, 0, stream>>>(Wl, WlT, 128, 256, 128 * 256);
    convert_wt_kernel<<<(5 * 256 * 512 + 255) / 256, 256, 0, stream>>>(W1, W1T, 256, 512, 5 * 256 * 512);
    convert_wt_kernel<<<(5 * 512 * 256 + 255) / 256, 256, 0, stream>>>(W2, W2T, 512, 256, 5 * 512 * 256);

    const int mtiles = (N + BM - 1) / BM;
    const int total4 = N * 64;          // N*256/4
    const int ew_blocks = (total4 + 255) / 256;
    const int eb = (E + 3) / 4;
    const int SB = 400;
    const int rpb = (N + SB - 1) / SB;

    // h = relu(x @ Wl + bl)
    gemm_kernel<float, float, 1><<<dim3(mtiles, 256 / BN), 256, 0, stream>>>(
        x, WlT, bl, h, N, 128, 256);

    for (int l = 0; l < 5; ++l) {
        build_table_kernel<<<10, 256, 0, stream>>>(E1, E2, l, tab, selfemb, sums);
        init_agg_kernel<<<ew_blocks, 256, 0, stream>>>(h, selfemb, agg, total4);
        scatter_kernel<<<eb, 256, 0, stream>>>(h, ei, ea, tab, agg, E);
        // hid = relu(agg @ W1[l] + b1[l])  (bf16 out)
        gemm_kernel<float, __bf16, 1><<<dim3(mtiles, 512 / BN), 256, 0, stream>>>(
            agg, W1T + (size_t)l * 512 * 256, b1 + l * 512, hid, N, 256, 512);
        // out = hid @ W2[l] + b2[l]  (fp32, reuse agg buffer)
        gemm_kernel<__bf16, float, 0><<<dim3(mtiles, 256 / BN), 256, 0, stream>>>(
            hid, W2T + (size_t)l * 256 * 512, b2 + l * 256, agg, N, 512, 256);
        bn_stats_kernel<<<SB, 256, 0, stream>>>(agg, sums, N, rpb);
        bn_finalize_kernel<<<1, 256, 0, stream>>>(sums, gamma, beta, l, N, scsh);
        bn_apply_kernel<<<ew_blocks, 256, 0, stream>>>(agg, scsh, h, total4);
    }
}

// Round 2
// 2491.817 us; speedup vs baseline: 3.4811x; 3.4811x over previous
//
#include <hip/hip_runtime.h>
#include <hip/hip_bf16.h>

// ---------------------------------------------------------------------------
// GNN pretrain forward: h=relu(x@Wl+bl); 5x [gather-agg -> MLP -> batchnorm]
// N=100000 nodes, E=400000 edges, DIM=256, hidden 512.
// R2: replaced atomic scatter (6.7ms, 1.6GB HBM writes/layer) with a
// once-per-launch counting sort by dst + per-node gather (no atomics).
// ---------------------------------------------------------------------------

typedef __bf16 bf16x8 __attribute__((ext_vector_type(8)));
typedef float f32x4 __attribute__((ext_vector_type(4)));

#define BM 64
#define BN 64
#define BK 32

// C[M x Nc] = act(A[M x K] @ BT[Nc x K]^T + bias), A fp32 or bf16, C fp32 or bf16
template<typename AT, typename CT, int RELU>
__global__ __launch_bounds__(256)
void gemm_kernel(const void* __restrict__ Av, const __bf16* __restrict__ BT,
                 const float* __restrict__ bias, void* __restrict__ Cv,
                 int M, int K, int Nc)
{
    __shared__ __bf16 As[BM][BK];
    __shared__ __bf16 Bs[BN][BK];

    const int tid  = threadIdx.x;
    const int wave = tid >> 6;
    const int lane = tid & 63;
    const int quad = lane >> 4;
    const int l16  = lane & 15;

    const int row0 = blockIdx.x * BM;
    const int col0 = blockIdx.y * BN;

    f32x4 acc[4];
#pragma unroll
    for (int t = 0; t < 4; ++t) acc[t] = (f32x4){0.f, 0.f, 0.f, 0.f};

    const int srow = tid >> 2;        // 0..63
    const int scol = (tid & 3) * 8;   // 0,8,16,24

    const int a_row = row0 + srow;
    const bool a_ok = (a_row < M);
    const __bf16* Bp = BT + (size_t)(col0 + srow) * K + scol;

    for (int k0 = 0; k0 < K; k0 += BK) {
        bf16x8 aval;
        if constexpr (sizeof(AT) == 4) {
            const float* Ap = (const float*)Av + (size_t)a_row * K + k0 + scol;
            f32x4 x0 = {0.f,0.f,0.f,0.f}, x1 = {0.f,0.f,0.f,0.f};
            if (a_ok) { x0 = *(const f32x4*)(Ap); x1 = *(const f32x4*)(Ap + 4); }
#pragma unroll
            for (int j = 0; j < 4; ++j) {
                aval[j]     = (__bf16)x0[j];
                aval[4 + j] = (__bf16)x1[j];
            }
        } else {
            const __bf16* Ap = (const __bf16*)Av + (size_t)a_row * K + k0 + scol;
            if (a_ok) aval = *(const bf16x8*)Ap;
            else {
#pragma unroll
                for (int j = 0; j < 8; ++j) aval[j] = (__bf16)0.f;
            }
        }
        bf16x8 bval = *(const bf16x8*)(Bp + k0);

        __syncthreads();
        *(bf16x8*)&As[srow][scol] = aval;
        *(bf16x8*)&Bs[srow][scol] = bval;
        __syncthreads();

        bf16x8 af = *(const bf16x8*)&As[wave * 16 + l16][quad * 8];
#pragma unroll
        for (int t = 0; t < 4; ++t) {
            bf16x8 bf = *(const bf16x8*)&Bs[t * 16 + l16][quad * 8];
            acc[t] = __builtin_amdgcn_mfma_f32_16x16x32_bf16(af, bf, acc[t], 0, 0, 0);
        }
    }

#pragma unroll
    for (int t = 0; t < 4; ++t) {
        const int col = col0 + t * 16 + l16;
        const float b = bias[col];
#pragma unroll
        for (int r = 0; r < 4; ++r) {
            const int row = row0 + wave * 16 + quad * 4 + r;
            if (row < M) {
                float v = acc[t][r] + b;
                if (RELU) v = fmaxf(v, 0.f);
                if constexpr (sizeof(CT) == 4)
                    ((float*)Cv)[(size_t)row * Nc + col] = v;
                else
                    ((__bf16*)Cv)[(size_t)row * Nc + col] = (__bf16)v;
            }
        }
    }
}

// WT[l][n][k] = (bf16) W[l][k][n]
__global__ void convert_wt_kernel(const float* __restrict__ W, __bf16* __restrict__ WT,
                                  int K, int Nc, int total)
{
    int i = blockIdx.x * 256 + threadIdx.x;
    if (i >= total) return;
    int kn = K * Nc;
    int l = i / kn;
    int rem = i - l * kn;
    int n = rem / K;
    int k = rem - n * K;
    WT[i] = (__bf16)W[(size_t)l * kn + (size_t)k * Nc + n];
}

// ------------------------ edge sort (once per launch) ----------------------

__global__ void zero_counts_kernel(int* __restrict__ counts, int N)
{
    int i = blockIdx.x * 256 + threadIdx.x;
    if (i < N) counts[i] = 0;
}

__global__ void hist_kernel(const int* __restrict__ ei, int* __restrict__ counts, int E)
{
    int e = blockIdx.x * 256 + threadIdx.x;
    if (e < E) atomicAdd(&counts[ei[E + e]], 1);
}

// per-256-chunk exclusive scan + chunk totals
__global__ void scan1_kernel(const int* __restrict__ counts, int* __restrict__ partial,
                             int* __restrict__ blocksums, int N)
{
    __shared__ int sm[256];
    int i = blockIdx.x * 256 + threadIdx.x;
    int v = (i < N) ? counts[i] : 0;
    sm[threadIdx.x] = v;
    __syncthreads();
    for (int off = 1; off < 256; off <<= 1) {
        int t = 0;
        if ((int)threadIdx.x >= off) t = sm[threadIdx.x - off];
        __syncthreads();
        if ((int)threadIdx.x >= off) sm[threadIdx.x] += t;
        __syncthreads();
    }
    if (i < N) partial[i] = sm[threadIdx.x] - v;  // exclusive within chunk
    if (threadIdx.x == 255) blocksums[blockIdx.x] = sm[255];
}

// single-block exclusive scan of chunk totals (NB <= 1024)
__global__ void scan2_kernel(int* __restrict__ blocksums, int NB)
{
    __shared__ int sm[1024];
    int v = ((int)threadIdx.x < NB) ? blocksums[threadIdx.x] : 0;
    sm[threadIdx.x] = v;
    __syncthreads();
    for (int off = 1; off < 1024; off <<= 1) {
        int t = 0;
        if ((int)threadIdx.x >= off) t = sm[threadIdx.x - off];
        __syncthreads();
        if ((int)threadIdx.x >= off) sm[threadIdx.x] += t;
        __syncthreads();
    }
    if ((int)threadIdx.x < NB) blocksums[threadIdx.x] = sm[threadIdx.x] - v;
}

__global__ void scan3_kernel(const int* __restrict__ partial, const int* __restrict__ blocksums,
                             int* __restrict__ rowptr, int* __restrict__ woff, int N, int E)
{
    int i = blockIdx.x * 256 + threadIdx.x;
    if (i < N) {
        int v = partial[i] + blocksums[blockIdx.x];
        rowptr[i] = v;
        woff[i] = v;
    }
    if (i == 0) rowptr[N] = E;
}

// sorted[pos] = (src<<4)|class for edges grouped by dst
__global__ void scatter_sort_kernel(const int* __restrict__ ei, const int* __restrict__ ea,
                                    int* __restrict__ woff, int* __restrict__ sorted, int E)
{
    int e = blockIdx.x * 256 + threadIdx.x;
    if (e >= E) return;
    int dst = ei[E + e];
    int src = ei[e];
    int c = ea[2 * e] * 3 + ea[2 * e + 1];
    int pos = atomicAdd(&woff[dst], 1);
    sorted[pos] = (src << 4) | c;
}

// ------------------------ per-layer kernels --------------------------------

// tab[c=bt*3+bd][256] = E1[l][bt] + E2[l][bd]; selfemb = E1[l][4]+E2[l][0]; zero sums
__global__ void build_table_kernel(const float* __restrict__ E1, const float* __restrict__ E2,
                                   int l, float* __restrict__ tab, float* __restrict__ selfemb,
                                   float* __restrict__ sums)
{
    int b = blockIdx.x;
    int t = threadIdx.x;
    const float* e1 = E1 + (size_t)l * 6 * 256;
    const float* e2 = E2 + (size_t)l * 3 * 256;
    if (b < 9) {
        tab[b * 256 + t] = e1[(b / 3) * 256 + t] + e2[(b % 3) * 256 + t];
    } else {
        selfemb[t] = e1[4 * 256 + t] + e2[0 * 256 + t];
        sums[t] = 0.f;
        sums[256 + t] = 0.f;
    }
}

// agg[n] = h[n] + selfemb + sum_{e in edges(n)} (h[src_e] + tab[c_e])
// 4 nodes/block, one 64-lane wave per node, 4 floats/lane.
__global__ __launch_bounds__(256)
void gather_kernel(const float* __restrict__ h, const int* __restrict__ rowptr,
                   const int* __restrict__ sorted, const float* __restrict__ tab,
                   const float* __restrict__ selfemb, float* __restrict__ agg, int N)
{
    __shared__ float stab[10 * 256];  // 9x256 tab + selfemb
    for (int j = threadIdx.x; j < 9 * 256; j += 256) stab[j] = tab[j];
    if (threadIdx.x < 256) stab[9 * 256 + threadIdx.x] = selfemb[threadIdx.x];
    __syncthreads();

    int n = blockIdx.x * 4 + (threadIdx.x >> 6);
    if (n >= N) return;
    int lane = threadIdx.x & 63;
    int f = lane * 4;

    int r0 = rowptr[n];
    int r1 = rowptr[n + 1];

    f32x4 acc = *(const f32x4*)(h + (size_t)n * 256 + f)
              + *(const f32x4*)(stab + 9 * 256 + f);
    for (int e = r0; e < r1; ++e) {
        int v = sorted[e];
        int src = v >> 4;
        int c = v & 15;
        f32x4 hv = *(const f32x4*)(h + (size_t)src * 256 + f);
        f32x4 tv = *(const f32x4*)(stab + c * 256 + f);
        acc += hv + tv;
    }
    *(f32x4*)(agg + (size_t)n * 256 + f) = acc;
}

// column sums / sumsq over rows (256 cols)
__global__ __launch_bounds__(256)
void bn_stats_kernel(const float* __restrict__ out, float* __restrict__ sums,
                     int M, int rows_per_block)
{
    int col = threadIdx.x;
    int r0 = blockIdx.x * rows_per_block;
    int r1 = min(M, r0 + rows_per_block);
    float s = 0.f, ss = 0.f;
    for (int r = r0; r < r1; ++r) {
        float v = out[(size_t)r * 256 + col];
        s += v;
        ss += v * v;
    }
    atomicAdd(&sums[col], s);
    atomicAdd(&sums[256 + col], ss);
}

__global__ void bn_finalize_kernel(const float* __restrict__ sums,
                                   const float* __restrict__ gamma,
                                   const float* __restrict__ beta,
                                   int l, int M, float* __restrict__ scsh)
{
    int c = threadIdx.x;  // 256
    float inv = 1.f / (float)M;
    float mean = sums[c] * inv;
    float var = sums[256 + c] * inv - mean * mean;
    float sc = gamma[l * 256 + c] * rsqrtf(var + 1e-5f);
    scsh[c] = sc;
    scsh[256 + c] = beta[l * 256 + c] - mean * sc;
}

// h = out * scale + shift
__global__ __launch_bounds__(256)
void bn_apply_kernel(const float* __restrict__ out, const float* __restrict__ scsh,
                     float* __restrict__ h, int total4)
{
    int i = blockIdx.x * 256 + threadIdx.x;
    if (i >= total4) return;
    int cg = i & 63;
    f32x4 sc = ((const f32x4*)scsh)[cg];
    f32x4 sh = ((const f32x4*)scsh)[64 + cg];
    f32x4 v = ((const f32x4*)out)[i];
    ((f32x4*)h)[i] = v * sc + sh;
}

extern "C" void kernel_launch(void* const* d_in, const int* in_sizes, int n_in,
                              void* d_out, int out_size, void* d_ws, size_t ws_size,
                              hipStream_t stream)
{
    const float* x     = (const float*)d_in[0];
    const int*   ei    = (const int*)d_in[1];
    const int*   ea    = (const int*)d_in[2];
    const float* Wl    = (const float*)d_in[3];
    const float* bl    = (const float*)d_in[4];
    const float* W1    = (const float*)d_in[5];
    const float* b1    = (const float*)d_in[6];
    const float* W2    = (const float*)d_in[7];
    const float* b2    = (const float*)d_in[8];
    const float* E1    = (const float*)d_in[9];
    const float* E2    = (const float*)d_in[10];
    const float* gamma = (const float*)d_in[11];
    const float* beta  = (const float*)d_in[12];

    const int N = in_sizes[0] / 128;
    const int E = in_sizes[1] / 2;

    // workspace layout
    float*  h    = (float*)d_out;                    // N x 256 fp32 (final out)
    float*  agg  = (float*)d_ws;                     // N x 256 fp32 (also gemm2 out)
    __bf16* hid  = (__bf16*)(agg + (size_t)N * 256); // N x 512 bf16
    __bf16* WlT  = hid + (size_t)N * 512;            // 256 x 128
    __bf16* W1T  = WlT + 256 * 128;                  // 5 x 512 x 256
    __bf16* W2T  = W1T + 5 * 512 * 256;              // 5 x 256 x 512
    float*  tab  = (float*)(W2T + 5 * 256 * 512);    // 9 x 256
    float*  selfemb = tab + 9 * 256;                 // 256
    float*  sums = selfemb + 256;                    // 512
    float*  scsh = sums + 512;                       // 512
    int*    counts = (int*)(scsh + 512);             // N
    int*    partial = counts + N;                    // N
    int*    rowptr  = partial + N;                   // N+1
    int*    woff    = rowptr + N + 1;                // N
    int*    sorted  = woff + N;                      // E
    int*    blocksums = sorted + E;                  // <=1024

    const int NB = (N + 255) / 256;   // scan chunks (must be <= 1024)
    const int EB = (E + 255) / 256;

    // --- edge sort by dst (edges constant across layers) ---
    zero_counts_kernel<<<NB, 256, 0, stream>>>(counts, N);
    hist_kernel<<<EB, 256, 0, stream>>>(ei, counts, E);
    scan1_kernel<<<NB, 256, 0, stream>>>(counts, partial, blocksums, N);
    scan2_kernel<<<1, 1024, 0, stream>>>(blocksums, NB);
    scan3_kernel<<<NB, 256, 0, stream>>>(partial, blocksums, rowptr, woff, N, E);
    scatter_sort_kernel<<<EB, 256, 0, stream>>>(ei, ea, woff, sorted, E);

    // --- weight conversion (transposed bf16) ---
    convert_wt_kernel<<<(128 * 256 + 255) / 256, 256, 0, stream>>>(Wl, WlT, 128, 256, 128 * 256);
    convert_wt_kernel<<<(5 * 256 * 512 + 255) / 256, 256, 0, stream>>>(W1, W1T, 256, 512, 5 * 256 * 512);
    convert_wt_kernel<<<(5 * 512 * 256 + 255) / 256, 256, 0, stream>>>(W2, W2T, 512, 256, 5 * 512 * 256);

    const int mtiles = (N + BM - 1) / BM;
    const int total4 = N * 64;          // N*256/4
    const int ew_blocks = (total4 + 255) / 256;
    const int gb = (N + 3) / 4;
    const int SB = 400;
    const int rpb = (N + SB - 1) / SB;

    // h = relu(x @ Wl + bl)
    gemm_kernel<float, float, 1><<<dim3(mtiles, 256 / BN), 256, 0, stream>>>(
        x, WlT, bl, h, N, 128, 256);

    for (int l = 0; l < 5; ++l) {
        build_table_kernel<<<10, 256, 0, stream>>>(E1, E2, l, tab, selfemb, sums);
        gather_kernel<<<gb, 256, 0, stream>>>(h, rowptr, sorted, tab, selfemb, agg, N);
        // hid = relu(agg @ W1[l] + b1[l])  (bf16 out)
        gemm_kernel<float, __bf16, 1><<<dim3(mtiles, 512 / BN), 256, 0, stream>>>(
            agg, W1T + (size_t)l * 512 * 256, b1 + l * 512, hid, N, 256, 512);
        // out = hid @ W2[l] + b2[l]  (fp32, reuse agg buffer)
        gemm_kernel<__bf16, float, 0><<<dim3(mtiles, 256 / BN), 256, 0, stream>>>(
            hid, W2T + (size_t)l * 256 * 512, b2 + l * 256, agg, N, 512, 256);
        bn_stats_kernel<<<SB, 256, 0, stream>>>(agg, sums, N, rpb);
        bn_finalize_kernel<<<1, 256, 0, stream>>>(sums, gamma, beta, l, N, scsh);
        bn_apply_kernel<<<ew_blocks, 256, 0, stream>>>(agg, scsh, h, total4);
    }
}

// Round 3
// 1684.806 us; speedup vs baseline: 5.1486x; 1.4790x over previous
//
#include <hip/hip_runtime.h>
#include <hip/hip_bf16.h>

// ---------------------------------------------------------------------------
// GNN pretrain forward: h=relu(x@Wl+bl); 5x [gather-agg -> MLP -> batchnorm]
// R3: 128x128 GEMM tiles, grid=(ntile,mtile) for L3 A-reuse, LDS pad 40,
// gather fuses BN-apply of previous layer + writes bf16 agg (in d_out space),
// gemm2 fuses BN stats (column sums via shuffle + atomics).
// ---------------------------------------------------------------------------

typedef __bf16 bf16x8 __attribute__((ext_vector_type(8)));
typedef __bf16 bf16x4 __attribute__((ext_vector_type(4)));
typedef float f32x4 __attribute__((ext_vector_type(4)));

#define LDSTRIDE 40  // bf16 elems per LDS row (80B = 20 banks, odd*4 -> ~2-way max)

// C[M x Nc] = act(A[M x K] @ BT[Nc x K]^T + bias)
// 128x128 block tile, 4 waves (2x2), each wave 64x64 = 4x4 MFMA tiles.
template<typename AT, typename CT, int RELU, int STATS>
__global__ __launch_bounds__(256, 2)
void gemm_kernel(const void* __restrict__ Av, const __bf16* __restrict__ BT,
                 const float* __restrict__ bias, void* __restrict__ Cv,
                 float* __restrict__ sums, int M, int K, int Nc)
{
    __shared__ __bf16 As[128 * LDSTRIDE];
    __shared__ __bf16 Bs[128 * LDSTRIDE];

    const int tid  = threadIdx.x;
    const int wave = tid >> 6;
    const int lane = tid & 63;
    const int quad = lane >> 4;
    const int l16  = lane & 15;
    const int wm   = wave >> 1;
    const int wn   = wave & 1;

    const int col0 = blockIdx.x * 128;
    const int row0 = blockIdx.y * 128;

    f32x4 acc[4][4];
#pragma unroll
    for (int mt = 0; mt < 4; ++mt)
#pragma unroll
        for (int nt = 0; nt < 4; ++nt) acc[mt][nt] = (f32x4){0.f, 0.f, 0.f, 0.f};

    // staging: 256 threads, each loads 16 elems of one row (128 rows x 32 cols)
    const int srow = tid >> 1;
    const int scol = (tid & 1) * 16;

    const int a_row = row0 + srow;
    const bool a_ok = (a_row < M);
    const __bf16* Bp = BT + (size_t)(col0 + srow) * K + scol;

    for (int k0 = 0; k0 < K; k0 += 32) {
        bf16x8 a0, a1;
        if constexpr (sizeof(AT) == 4) {
            const float* Ap = (const float*)Av + (size_t)a_row * K + k0 + scol;
            f32x4 x0 = {0,0,0,0}, x1 = {0,0,0,0}, x2 = {0,0,0,0}, x3 = {0,0,0,0};
            if (a_ok) {
                x0 = *(const f32x4*)(Ap);
                x1 = *(const f32x4*)(Ap + 4);
                x2 = *(const f32x4*)(Ap + 8);
                x3 = *(const f32x4*)(Ap + 12);
            }
#pragma unroll
            for (int j = 0; j < 4; ++j) {
                a0[j] = (__bf16)x0[j]; a0[4 + j] = (__bf16)x1[j];
                a1[j] = (__bf16)x2[j]; a1[4 + j] = (__bf16)x3[j];
            }
        } else {
            if (a_ok) {
                const __bf16* Ap = (const __bf16*)Av + (size_t)a_row * K + k0 + scol;
                a0 = *(const bf16x8*)Ap;
                a1 = *(const bf16x8*)(Ap + 8);
            } else {
#pragma unroll
                for (int j = 0; j < 8; ++j) { a0[j] = (__bf16)0.f; a1[j] = (__bf16)0.f; }
            }
        }
        bf16x8 b0 = *(const bf16x8*)(Bp + k0);
        bf16x8 b1 = *(const bf16x8*)(Bp + k0 + 8);

        __syncthreads();
        *(bf16x8*)&As[srow * LDSTRIDE + scol]     = a0;
        *(bf16x8*)&As[srow * LDSTRIDE + scol + 8] = a1;
        *(bf16x8*)&Bs[srow * LDSTRIDE + scol]     = b0;
        *(bf16x8*)&Bs[srow * LDSTRIDE + scol + 8] = b1;
        __syncthreads();

        bf16x8 af[4], bfr[4];
#pragma unroll
        for (int mt = 0; mt < 4; ++mt)
            af[mt] = *(const bf16x8*)&As[(wm * 64 + mt * 16 + l16) * LDSTRIDE + quad * 8];
#pragma unroll
        for (int nt = 0; nt < 4; ++nt)
            bfr[nt] = *(const bf16x8*)&Bs[(wn * 64 + nt * 16 + l16) * LDSTRIDE + quad * 8];

#pragma unroll
        for (int mt = 0; mt < 4; ++mt)
#pragma unroll
            for (int nt = 0; nt < 4; ++nt)
                acc[mt][nt] = __builtin_amdgcn_mfma_f32_16x16x32_bf16(
                    af[mt], bfr[nt], acc[mt][nt], 0, 0, 0);
    }

    // epilogue: D col = nt*16+l16 (within wave), row = mt*16 + quad*4 + r
#pragma unroll
    for (int nt = 0; nt < 4; ++nt) {
        const int col = col0 + wn * 64 + nt * 16 + l16;
        const float b = bias[col];
        float s = 0.f, ss = 0.f;
#pragma unroll
        for (int mt = 0; mt < 4; ++mt) {
#pragma unroll
            for (int r = 0; r < 4; ++r) {
                const int row = row0 + wm * 64 + mt * 16 + quad * 4 + r;
                if (row < M) {
                    float v = acc[mt][nt][r] + b;
                    if (RELU) v = fmaxf(v, 0.f);
                    if constexpr (sizeof(CT) == 4)
                        ((float*)Cv)[(size_t)row * Nc + col] = v;
                    else
                        ((__bf16*)Cv)[(size_t)row * Nc + col] = (__bf16)v;
                    if (STATS) { s += v; ss += v * v; }
                }
            }
        }
        if (STATS) {
            s += __shfl_xor(s, 16); ss += __shfl_xor(ss, 16);
            s += __shfl_xor(s, 32); ss += __shfl_xor(ss, 32);
            if (lane < 16) {
                atomicAdd(&sums[col], s);
                atomicAdd(&sums[256 + col], ss);
            }
        }
    }
}

// WT[l][n][k] = (bf16) W[l][k][n]
__global__ void convert_wt_kernel(const float* __restrict__ W, __bf16* __restrict__ WT,
                                  int K, int Nc, int total)
{
    int i = blockIdx.x * 256 + threadIdx.x;
    if (i >= total) return;
    int kn = K * Nc;
    int l = i / kn;
    int rem = i - l * kn;
    int n = rem / K;
    int k = rem - n * K;
    WT[i] = (__bf16)W[(size_t)l * kn + (size_t)k * Nc + n];
}

// ------------------------ edge sort (once per launch) ----------------------

__global__ void zero_counts_kernel(int* __restrict__ counts, int N)
{
    int i = blockIdx.x * 256 + threadIdx.x;
    if (i < N) counts[i] = 0;
}

__global__ void hist_kernel(const int* __restrict__ ei, int* __restrict__ counts, int E)
{
    int e = blockIdx.x * 256 + threadIdx.x;
    if (e < E) atomicAdd(&counts[ei[E + e]], 1);
}

__global__ void scan1_kernel(const int* __restrict__ counts, int* __restrict__ partial,
                             int* __restrict__ blocksums, int N)
{
    __shared__ int sm[256];
    int i = blockIdx.x * 256 + threadIdx.x;
    int v = (i < N) ? counts[i] : 0;
    sm[threadIdx.x] = v;
    __syncthreads();
    for (int off = 1; off < 256; off <<= 1) {
        int t = 0;
        if ((int)threadIdx.x >= off) t = sm[threadIdx.x - off];
        __syncthreads();
        if ((int)threadIdx.x >= off) sm[threadIdx.x] += t;
        __syncthreads();
    }
    if (i < N) partial[i] = sm[threadIdx.x] - v;
    if (threadIdx.x == 255) blocksums[blockIdx.x] = sm[255];
}

__global__ void scan2_kernel(int* __restrict__ blocksums, int NB)
{
    __shared__ int sm[1024];
    int v = ((int)threadIdx.x < NB) ? blocksums[threadIdx.x] : 0;
    sm[threadIdx.x] = v;
    __syncthreads();
    for (int off = 1; off < 1024; off <<= 1) {
        int t = 0;
        if ((int)threadIdx.x >= off) t = sm[threadIdx.x - off];
        __syncthreads();
        if ((int)threadIdx.x >= off) sm[threadIdx.x] += t;
        __syncthreads();
    }
    if ((int)threadIdx.x < NB) blocksums[threadIdx.x] = sm[threadIdx.x] - v;
}

__global__ void scan3_kernel(const int* __restrict__ partial, const int* __restrict__ blocksums,
                             int* __restrict__ rowptr, int* __restrict__ woff, int N, int E)
{
    int i = blockIdx.x * 256 + threadIdx.x;
    if (i < N) {
        int v = partial[i] + blocksums[blockIdx.x];
        rowptr[i] = v;
        woff[i] = v;
    }
    if (i == 0) rowptr[N] = E;
}

__global__ void scatter_sort_kernel(const int* __restrict__ ei, const int* __restrict__ ea,
                                    int* __restrict__ woff, int* __restrict__ sorted, int E)
{
    int e = blockIdx.x * 256 + threadIdx.x;
    if (e >= E) return;
    int dst = ei[E + e];
    int src = ei[e];
    int c = ea[2 * e] * 3 + ea[2 * e + 1];
    int pos = atomicAdd(&woff[dst], 1);
    sorted[pos] = (src << 4) | c;
}

// ------------------------ per-layer kernels --------------------------------

__global__ void build_table_kernel(const float* __restrict__ E1, const float* __restrict__ E2,
                                   int l, float* __restrict__ tab, float* __restrict__ selfemb,
                                   float* __restrict__ sums)
{
    int b = blockIdx.x;
    int t = threadIdx.x;
    const float* e1 = E1 + (size_t)l * 6 * 256;
    const float* e2 = E2 + (size_t)l * 3 * 256;
    if (b < 9) {
        tab[b * 256 + t] = e1[(b / 3) * 256 + t] + e2[(b % 3) * 256 + t];
    } else {
        selfemb[t] = e1[4 * 256 + t] + e2[0 * 256 + t];
        sums[t] = 0.f;
        sums[256 + t] = 0.f;
    }
}

// aggb[n] = bf16( bn(out[n]) + selfemb + sum_e (bn(out[src_e]) + tab[c_e]) )
// where bn(v) = v*scale[col] + shift[col] (identity when APPLY_BN=0).
// 4 nodes/block, one 64-lane wave per node, 4 floats/lane.
template<int APPLY_BN>
__global__ __launch_bounds__(256)
void gather_kernel(const float* __restrict__ out, const int* __restrict__ rowptr,
                   const int* __restrict__ sorted, const float* __restrict__ tab,
                   const float* __restrict__ selfemb, const float* __restrict__ scsh,
                   __bf16* __restrict__ aggb, int N)
{
    __shared__ float stab[10 * 256];
    __shared__ float ssc[512];
    for (int j = threadIdx.x; j < 9 * 256; j += 256) stab[j] = tab[j];
    if (threadIdx.x < 256) stab[9 * 256 + threadIdx.x] = selfemb[threadIdx.x];
    if (APPLY_BN) {
        if (threadIdx.x < 256) {
            ssc[threadIdx.x] = scsh[threadIdx.x];
            ssc[256 + threadIdx.x] = scsh[256 + threadIdx.x];
        }
    }
    __syncthreads();

    int n = blockIdx.x * 4 + (threadIdx.x >> 6);
    if (n >= N) return;
    int lane = threadIdx.x & 63;
    int f = lane * 4;

    f32x4 sc, sh;
    if (APPLY_BN) {
        sc = ((const f32x4*)ssc)[lane];
        sh = ((const f32x4*)(ssc + 256))[lane];
    }

    int r0 = rowptr[n];
    int r1 = rowptr[n + 1];

    f32x4 hv = *(const f32x4*)(out + (size_t)n * 256 + f);
    if (APPLY_BN) hv = hv * sc + sh;
    f32x4 acc = hv + *(const f32x4*)(stab + 9 * 256 + f);

    for (int e = r0; e < r1; ++e) {
        int v = sorted[e];
        int src = v >> 4;
        int c = v & 15;
        f32x4 xv = *(const f32x4*)(out + (size_t)src * 256 + f);
        if (APPLY_BN) xv = xv * sc + sh;
        acc += xv + *(const f32x4*)(stab + c * 256 + f);
    }
    bf16x4 o;
#pragma unroll
    for (int j = 0; j < 4; ++j) o[j] = (__bf16)acc[j];
    *(bf16x4*)(aggb + (size_t)n * 256 + f) = o;
}

__global__ void bn_finalize_kernel(const float* __restrict__ sums,
                                   const float* __restrict__ gamma,
                                   const float* __restrict__ beta,
                                   int l, int M, float* __restrict__ scsh)
{
    int c = threadIdx.x;  // 256
    float inv = 1.f / (float)M;
    float mean = sums[c] * inv;
    float var = sums[256 + c] * inv - mean * mean;
    float sc = gamma[l * 256 + c] * rsqrtf(var + 1e-5f);
    scsh[c] = sc;
    scsh[256 + c] = beta[l * 256 + c] - mean * sc;
}

// h = out * scale + shift  (final layer only)
__global__ __launch_bounds__(256)
void bn_apply_kernel(const float* __restrict__ out, const float* __restrict__ scsh,
                     float* __restrict__ h, int total4)
{
    int i = blockIdx.x * 256 + threadIdx.x;
    if (i >= total4) return;
    int cg = i & 63;
    f32x4 sc = ((const f32x4*)scsh)[cg];
    f32x4 sh = ((const f32x4*)scsh)[64 + cg];
    f32x4 v = ((const f32x4*)out)[i];
    ((f32x4*)h)[i] = v * sc + sh;
}

extern "C" void kernel_launch(void* const* d_in, const int* in_sizes, int n_in,
                              void* d_out, int out_size, void* d_ws, size_t ws_size,
                              hipStream_t stream)
{
    const float* x     = (const float*)d_in[0];
    const int*   ei    = (const int*)d_in[1];
    const int*   ea    = (const int*)d_in[2];
    const float* Wl    = (const float*)d_in[3];
    const float* bl    = (const float*)d_in[4];
    const float* W1    = (const float*)d_in[5];
    const float* b1    = (const float*)d_in[6];
    const float* W2    = (const float*)d_in[7];
    const float* b2    = (const float*)d_in[8];
    const float* E1    = (const float*)d_in[9];
    const float* E2    = (const float*)d_in[10];
    const float* gamma = (const float*)d_in[11];
    const float* beta  = (const float*)d_in[12];

    const int N = in_sizes[0] / 128;
    const int E = in_sizes[1] / 2;

    // d_out space doubles as the bf16 agg buffer (N*256 bf16 = half of d_out);
    // the final bn_apply overwrites d_out with the fp32 result.
    __bf16* aggb = (__bf16*)d_out;               // N x 256 bf16
    float*  hfin = (float*)d_out;                // final output view

    // workspace layout
    float*  out  = (float*)d_ws;                     // N x 256 fp32 (gemm0/gemm2 out)
    __bf16* hid  = (__bf16*)(out + (size_t)N * 256); // N x 512 bf16
    __bf16* WlT  = hid + (size_t)N * 512;            // 256 x 128
    __bf16* W1T  = WlT + 256 * 128;                  // 5 x 512 x 256
    __bf16* W2T  = W1T + 5 * 512 * 256;              // 5 x 256 x 512
    float*  tab  = (float*)(W2T + 5 * 256 * 512);    // 9 x 256
    float*  selfemb = tab + 9 * 256;                 // 256
    float*  sums = selfemb + 256;                    // 512
    float*  scsh = sums + 512;                       // 512
    int*    counts = (int*)(scsh + 512);             // N
    int*    partial = counts + N;                    // N
    int*    rowptr  = partial + N;                   // N+1
    int*    woff    = rowptr + N + 1;                // N
    int*    sorted  = woff + N;                      // E
    int*    blocksums = sorted + E;                  // <=1024

    const int NB = (N + 255) / 256;
    const int EB = (E + 255) / 256;

    // --- edge sort by dst (edges constant across layers) ---
    zero_counts_kernel<<<NB, 256, 0, stream>>>(counts, N);
    hist_kernel<<<EB, 256, 0, stream>>>(ei, counts, E);
    scan1_kernel<<<NB, 256, 0, stream>>>(counts, partial, blocksums, N);
    scan2_kernel<<<1, 1024, 0, stream>>>(blocksums, NB);
    scan3_kernel<<<NB, 256, 0, stream>>>(partial, blocksums, rowptr, woff, N, E);
    scatter_sort_kernel<<<EB, 256, 0, stream>>>(ei, ea, woff, sorted, E);

    // --- weight conversion (transposed bf16) ---
    convert_wt_kernel<<<(128 * 256 + 255) / 256, 256, 0, stream>>>(Wl, WlT, 128, 256, 128 * 256);
    convert_wt_kernel<<<(5 * 256 * 512 + 255) / 256, 256, 0, stream>>>(W1, W1T, 256, 512, 5 * 256 * 512);
    convert_wt_kernel<<<(5 * 512 * 256 + 255) / 256, 256, 0, stream>>>(W2, W2T, 512, 256, 5 * 512 * 256);

    const int mtiles = (N + 127) / 128;
    const int total4 = N * 64;
    const int ew_blocks = (total4 + 255) / 256;
    const int gb = (N + 3) / 4;

    // out = relu(x @ Wl + bl)   [grid: (ntiles, mtiles) so col-tiles share A via L3]
    gemm_kernel<float, float, 1, 0><<<dim3(2, mtiles), 256, 0, stream>>>(
        x, WlT, bl, out, nullptr, N, 128, 256);

    for (int l = 0; l < 5; ++l) {
        build_table_kernel<<<10, 256, 0, stream>>>(E1, E2, l, tab, selfemb, sums);
        if (l == 0)
            gather_kernel<0><<<gb, 256, 0, stream>>>(out, rowptr, sorted, tab, selfemb,
                                                     scsh, aggb, N);
        else
            gather_kernel<1><<<gb, 256, 0, stream>>>(out, rowptr, sorted, tab, selfemb,
                                                     scsh, aggb, N);
        // hid = relu(aggb @ W1[l] + b1[l])  (bf16 in, bf16 out)
        gemm_kernel<__bf16, __bf16, 1, 0><<<dim3(4, mtiles), 256, 0, stream>>>(
            aggb, W1T + (size_t)l * 512 * 256, b1 + l * 512, hid, nullptr, N, 256, 512);
        // out = hid @ W2[l] + b2[l]  (fp32 out, fused BN stats)
        gemm_kernel<__bf16, float, 0, 1><<<dim3(2, mtiles), 256, 0, stream>>>(
            hid, W2T + (size_t)l * 256 * 512, b2 + l * 256, out, sums, N, 512, 256);
        bn_finalize_kernel<<<1, 256, 0, stream>>>(sums, gamma, beta, l, N, scsh);
    }
    // final h = bn(out) -> d_out (fp32)
    bn_apply_kernel<<<ew_blocks, 256, 0, stream>>>(out, scsh, hfin, total4);
}

// Round 4
// 1586.624 us; speedup vs baseline: 5.4672x; 1.0619x over previous
//
#include <hip/hip_runtime.h>
#include <hip/hip_bf16.h>

// ---------------------------------------------------------------------------
// GNN pretrain forward: h=relu(x@Wl+bl); 5x [gather-agg -> fusedMLP -> BN]
// R4: gemm1+gemm2 fused into one kernel per layer. hid (64x512 per block)
// lives in LDS; A tile in registers; W1T/W2T streamed from L2. Kills the
// hid global round-trip (102MB write @1.8x amplification + 102MB read).
// ---------------------------------------------------------------------------

typedef __bf16 bf16x8 __attribute__((ext_vector_type(8)));
typedef __bf16 bf16x4 __attribute__((ext_vector_type(4)));
typedef float f32x4 __attribute__((ext_vector_type(4)));

#define LDSTRIDE 40  // gemm0 LDS pad

// ------------------- gemm0 (fp32 in, fp32 out, relu) -----------------------
// 128x128 block tile, 4 waves (2x2), each wave 64x64 = 4x4 MFMA tiles.
__global__ __launch_bounds__(256, 2)
void gemm0_kernel(const float* __restrict__ Av, const __bf16* __restrict__ BT,
                  const float* __restrict__ bias, float* __restrict__ Cv,
                  int M, int K, int Nc)
{
    __shared__ __bf16 As[128 * LDSTRIDE];
    __shared__ __bf16 Bs[128 * LDSTRIDE];

    const int tid  = threadIdx.x;
    const int wave = tid >> 6;
    const int lane = tid & 63;
    const int quad = lane >> 4;
    const int l16  = lane & 15;
    const int wm   = wave >> 1;
    const int wn   = wave & 1;

    const int col0 = blockIdx.x * 128;
    const int row0 = blockIdx.y * 128;

    f32x4 acc[4][4];
#pragma unroll
    for (int mt = 0; mt < 4; ++mt)
#pragma unroll
        for (int nt = 0; nt < 4; ++nt) acc[mt][nt] = (f32x4){0.f, 0.f, 0.f, 0.f};

    const int srow = tid >> 1;
    const int scol = (tid & 1) * 16;
    const int a_row = row0 + srow;
    const bool a_ok = (a_row < M);
    const __bf16* Bp = BT + (size_t)(col0 + srow) * K + scol;

    for (int k0 = 0; k0 < K; k0 += 32) {
        bf16x8 a0, a1;
        const float* Ap = Av + (size_t)a_row * K + k0 + scol;
        f32x4 x0 = {0,0,0,0}, x1 = {0,0,0,0}, x2 = {0,0,0,0}, x3 = {0,0,0,0};
        if (a_ok) {
            x0 = *(const f32x4*)(Ap);
            x1 = *(const f32x4*)(Ap + 4);
            x2 = *(const f32x4*)(Ap + 8);
            x3 = *(const f32x4*)(Ap + 12);
        }
#pragma unroll
        for (int j = 0; j < 4; ++j) {
            a0[j] = (__bf16)x0[j]; a0[4 + j] = (__bf16)x1[j];
            a1[j] = (__bf16)x2[j]; a1[4 + j] = (__bf16)x3[j];
        }
        bf16x8 b0 = *(const bf16x8*)(Bp + k0);
        bf16x8 b1 = *(const bf16x8*)(Bp + k0 + 8);

        __syncthreads();
        *(bf16x8*)&As[srow * LDSTRIDE + scol]     = a0;
        *(bf16x8*)&As[srow * LDSTRIDE + scol + 8] = a1;
        *(bf16x8*)&Bs[srow * LDSTRIDE + scol]     = b0;
        *(bf16x8*)&Bs[srow * LDSTRIDE + scol + 8] = b1;
        __syncthreads();

        bf16x8 af[4], bfr[4];
#pragma unroll
        for (int mt = 0; mt < 4; ++mt)
            af[mt] = *(const bf16x8*)&As[(wm * 64 + mt * 16 + l16) * LDSTRIDE + quad * 8];
#pragma unroll
        for (int nt = 0; nt < 4; ++nt)
            bfr[nt] = *(const bf16x8*)&Bs[(wn * 64 + nt * 16 + l16) * LDSTRIDE + quad * 8];

#pragma unroll
        for (int mt = 0; mt < 4; ++mt)
#pragma unroll
            for (int nt = 0; nt < 4; ++nt)
                acc[mt][nt] = __builtin_amdgcn_mfma_f32_16x16x32_bf16(
                    af[mt], bfr[nt], acc[mt][nt], 0, 0, 0);
    }

#pragma unroll
    for (int nt = 0; nt < 4; ++nt) {
        const int col = col0 + wn * 64 + nt * 16 + l16;
        const float b = bias[col];
#pragma unroll
        for (int mt = 0; mt < 4; ++mt) {
#pragma unroll
            for (int r = 0; r < 4; ++r) {
                const int row = row0 + wm * 64 + mt * 16 + quad * 4 + r;
                if (row < M) {
                    float v = fmaxf(acc[mt][nt][r] + b, 0.f);
                    Cv[(size_t)row * Nc + col] = v;
                }
            }
        }
    }
}

// ------------------- fused MLP: out = relu(A@W1+b1)@W2+b2 + BN stats -------
// M-tile = 64 rows/block, 256 threads (4 waves).
// Pass1: A frags in regs (reused over all hid cols), B streamed from global,
//        hid chunk -> LDS (bf16, stride 516).
// Pass2: out = hidS @ W2, fused column sums/sumsq via shuffle + atomics.
#define HS 516

__global__ __launch_bounds__(256, 2)
void fused_mlp_kernel(const __bf16* __restrict__ aggb,
                      const __bf16* __restrict__ W1T, const float* __restrict__ b1,
                      const __bf16* __restrict__ W2T, const float* __restrict__ b2,
                      float* __restrict__ out, float* __restrict__ sums, int M)
{
    __shared__ __bf16 hidS[64 * HS];

    const int tid  = threadIdx.x;
    const int wave = tid >> 6;
    const int lane = tid & 63;
    const int quad = lane >> 4;
    const int l16  = lane & 15;
    const int row0 = blockIdx.x * 64;

    // ---- A fragments into registers: A[m=mt*16+l16][k=kk*32+quad*8 ..+8) ----
    bf16x8 Afrag[4][8];
#pragma unroll
    for (int mt = 0; mt < 4; ++mt) {
        const int m = row0 + mt * 16 + l16;
        if (m < M) {
            const __bf16* Ap = aggb + (size_t)m * 256 + quad * 8;
#pragma unroll
            for (int kk = 0; kk < 8; ++kk)
                Afrag[mt][kk] = *(const bf16x8*)(Ap + kk * 32);
        } else {
#pragma unroll
            for (int kk = 0; kk < 8; ++kk)
#pragma unroll
                for (int j = 0; j < 8; ++j) Afrag[mt][kk][j] = (__bf16)0.f;
        }
    }

    // ---- pass 1: hid = relu(A @ W1 + b1), 4 chunks of 128 cols ----
    // wave covers 32 cols of each chunk (2 nt tiles).
#pragma unroll 1
    for (int c = 0; c < 4; ++c) {
        const int nbase = c * 128 + wave * 32;
        f32x4 acc1[4][2];
#pragma unroll
        for (int mt = 0; mt < 4; ++mt)
#pragma unroll
            for (int nt = 0; nt < 2; ++nt) acc1[mt][nt] = (f32x4){0.f, 0.f, 0.f, 0.f};

#pragma unroll
        for (int kk = 0; kk < 8; ++kk) {
            bf16x8 Bf[2];
#pragma unroll
            for (int nt = 0; nt < 2; ++nt)
                Bf[nt] = *(const bf16x8*)(W1T + (size_t)(nbase + nt * 16 + l16) * 256
                                          + kk * 32 + quad * 8);
#pragma unroll
            for (int mt = 0; mt < 4; ++mt)
#pragma unroll
                for (int nt = 0; nt < 2; ++nt)
                    acc1[mt][nt] = __builtin_amdgcn_mfma_f32_16x16x32_bf16(
                        Afrag[mt][kk], Bf[nt], acc1[mt][nt], 0, 0, 0);
        }

        // write chunk to LDS (bias + relu, bf16). row = mt*16+quad*4+r, col = nbase+nt*16+l16
#pragma unroll
        for (int nt = 0; nt < 2; ++nt) {
            const int col = nbase + nt * 16 + l16;
            const float bb = b1[col];
#pragma unroll
            for (int mt = 0; mt < 4; ++mt)
#pragma unroll
                for (int r = 0; r < 4; ++r) {
                    float v = fmaxf(acc1[mt][nt][r] + bb, 0.f);
                    hidS[(mt * 16 + quad * 4 + r) * HS + col] = (__bf16)v;
                }
        }
    }
    __syncthreads();

    // ---- pass 2: out = hidS @ W2 + b2 ; wave covers 64 of 256 out cols ----
    const int cb = wave * 64;
    f32x4 acc2[4][4];
#pragma unroll
    for (int mt = 0; mt < 4; ++mt)
#pragma unroll
        for (int nt = 0; nt < 4; ++nt) acc2[mt][nt] = (f32x4){0.f, 0.f, 0.f, 0.f};

#pragma unroll 2
    for (int kk = 0; kk < 16; ++kk) {
        bf16x8 Hf[4], Bf2[4];
#pragma unroll
        for (int mt = 0; mt < 4; ++mt)
            Hf[mt] = *(const bf16x8*)&hidS[(mt * 16 + l16) * HS + kk * 32 + quad * 8];
#pragma unroll
        for (int nt = 0; nt < 4; ++nt)
            Bf2[nt] = *(const bf16x8*)(W2T + (size_t)(cb + nt * 16 + l16) * 512
                                       + kk * 32 + quad * 8);
#pragma unroll
        for (int mt = 0; mt < 4; ++mt)
#pragma unroll
            for (int nt = 0; nt < 4; ++nt)
                acc2[mt][nt] = __builtin_amdgcn_mfma_f32_16x16x32_bf16(
                    Hf[mt], Bf2[nt], acc2[mt][nt], 0, 0, 0);
    }

    // ---- epilogue: bias + store fp32 + fused BN column stats ----
#pragma unroll
    for (int nt = 0; nt < 4; ++nt) {
        const int col = cb + nt * 16 + l16;
        const float bb = b2[col];
        float s = 0.f, ss = 0.f;
#pragma unroll
        for (int mt = 0; mt < 4; ++mt) {
#pragma unroll
            for (int r = 0; r < 4; ++r) {
                const int row = row0 + mt * 16 + quad * 4 + r;
                if (row < M) {
                    float v = acc2[mt][nt][r] + bb;
                    out[(size_t)row * 256 + col] = v;
                    s += v; ss += v * v;
                }
            }
        }
        s += __shfl_xor(s, 16); ss += __shfl_xor(ss, 16);
        s += __shfl_xor(s, 32); ss += __shfl_xor(ss, 32);
        if (lane < 16) {
            atomicAdd(&sums[col], s);
            atomicAdd(&sums[256 + col], ss);
        }
    }
}

// WT[l][n][k] = (bf16) W[l][k][n]
__global__ void convert_wt_kernel(const float* __restrict__ W, __bf16* __restrict__ WT,
                                  int K, int Nc, int total)
{
    int i = blockIdx.x * 256 + threadIdx.x;
    if (i >= total) return;
    int kn = K * Nc;
    int l = i / kn;
    int rem = i - l * kn;
    int n = rem / K;
    int k = rem - n * K;
    WT[i] = (__bf16)W[(size_t)l * kn + (size_t)k * Nc + n];
}

// ------------------------ edge sort (once per launch) ----------------------

__global__ void zero_counts_kernel(int* __restrict__ counts, int N)
{
    int i = blockIdx.x * 256 + threadIdx.x;
    if (i < N) counts[i] = 0;
}

__global__ void hist_kernel(const int* __restrict__ ei, int* __restrict__ counts, int E)
{
    int e = blockIdx.x * 256 + threadIdx.x;
    if (e < E) atomicAdd(&counts[ei[E + e]], 1);
}

__global__ void scan1_kernel(const int* __restrict__ counts, int* __restrict__ partial,
                             int* __restrict__ blocksums, int N)
{
    __shared__ int sm[256];
    int i = blockIdx.x * 256 + threadIdx.x;
    int v = (i < N) ? counts[i] : 0;
    sm[threadIdx.x] = v;
    __syncthreads();
    for (int off = 1; off < 256; off <<= 1) {
        int t = 0;
        if ((int)threadIdx.x >= off) t = sm[threadIdx.x - off];
        __syncthreads();
        if ((int)threadIdx.x >= off) sm[threadIdx.x] += t;
        __syncthreads();
    }
    if (i < N) partial[i] = sm[threadIdx.x] - v;
    if (threadIdx.x == 255) blocksums[blockIdx.x] = sm[255];
}

__global__ void scan2_kernel(int* __restrict__ blocksums, int NB)
{
    __shared__ int sm[1024];
    int v = ((int)threadIdx.x < NB) ? blocksums[threadIdx.x] : 0;
    sm[threadIdx.x] = v;
    __syncthreads();
    for (int off = 1; off < 1024; off <<= 1) {
        int t = 0;
        if ((int)threadIdx.x >= off) t = sm[threadIdx.x - off];
        __syncthreads();
        if ((int)threadIdx.x >= off) sm[threadIdx.x] += t;
        __syncthreads();
    }
    if ((int)threadIdx.x < NB) blocksums[threadIdx.x] = sm[threadIdx.x] - v;
}

__global__ void scan3_kernel(const int* __restrict__ partial, const int* __restrict__ blocksums,
                             int* __restrict__ rowptr, int* __restrict__ woff, int N, int E)
{
    int i = blockIdx.x * 256 + threadIdx.x;
    if (i < N) {
        int v = partial[i] + blocksums[blockIdx.x];
        rowptr[i] = v;
        woff[i] = v;
    }
    if (i == 0) rowptr[N] = E;
}

__global__ void scatter_sort_kernel(const int* __restrict__ ei, const int* __restrict__ ea,
                                    int* __restrict__ woff, int* __restrict__ sorted, int E)
{
    int e = blockIdx.x * 256 + threadIdx.x;
    if (e >= E) return;
    int dst = ei[E + e];
    int src = ei[e];
    int c = ea[2 * e] * 3 + ea[2 * e + 1];
    int pos = atomicAdd(&woff[dst], 1);
    sorted[pos] = (src << 4) | c;
}

// ------------------------ per-layer kernels --------------------------------

__global__ void build_table_kernel(const float* __restrict__ E1, const float* __restrict__ E2,
                                   int l, float* __restrict__ tab, float* __restrict__ selfemb,
                                   float* __restrict__ sums)
{
    int b = blockIdx.x;
    int t = threadIdx.x;
    const float* e1 = E1 + (size_t)l * 6 * 256;
    const float* e2 = E2 + (size_t)l * 3 * 256;
    if (b < 9) {
        tab[b * 256 + t] = e1[(b / 3) * 256 + t] + e2[(b % 3) * 256 + t];
    } else {
        selfemb[t] = e1[4 * 256 + t] + e2[0 * 256 + t];
        sums[t] = 0.f;
        sums[256 + t] = 0.f;
    }
}

// aggb[n] = bf16( bn(out[n]) + selfemb + sum_e (bn(out[src_e]) + tab[c_e]) )
// tab/selfemb read straight from global (10KB, L1-resident). No LDS.
template<int APPLY_BN>
__global__ __launch_bounds__(256)
void gather_kernel(const float* __restrict__ out, const int* __restrict__ rowptr,
                   const int* __restrict__ sorted, const float* __restrict__ tab,
                   const float* __restrict__ selfemb, const float* __restrict__ scsh,
                   __bf16* __restrict__ aggb, int N)
{
    int n = blockIdx.x * 4 + (threadIdx.x >> 6);
    if (n >= N) return;
    int lane = threadIdx.x & 63;
    int f = lane * 4;

    f32x4 sc, sh;
    if (APPLY_BN) {
        sc = *(const f32x4*)(scsh + f);
        sh = *(const f32x4*)(scsh + 256 + f);
    }

    int r0 = rowptr[n];
    int r1 = rowptr[n + 1];

    f32x4 hv = *(const f32x4*)(out + (size_t)n * 256 + f);
    if (APPLY_BN) hv = hv * sc + sh;
    f32x4 acc = hv + *(const f32x4*)(selfemb + f);

    for (int e = r0; e < r1; ++e) {
        int v = sorted[e];
        f32x4 xv = *(const f32x4*)(out + (size_t)(v >> 4) * 256 + f);
        if (APPLY_BN) xv = xv * sc + sh;
        acc += xv + *(const f32x4*)(tab + (v & 15) * 256 + f);
    }
    bf16x4 o;
#pragma unroll
    for (int j = 0; j < 4; ++j) o[j] = (__bf16)acc[j];
    *(bf16x4*)(aggb + (size_t)n * 256 + f) = o;
}

__global__ void bn_finalize_kernel(const float* __restrict__ sums,
                                   const float* __restrict__ gamma,
                                   const float* __restrict__ beta,
                                   int l, int M, float* __restrict__ scsh)
{
    int c = threadIdx.x;  // 256
    float inv = 1.f / (float)M;
    float mean = sums[c] * inv;
    float var = sums[256 + c] * inv - mean * mean;
    float sc = gamma[l * 256 + c] * rsqrtf(var + 1e-5f);
    scsh[c] = sc;
    scsh[256 + c] = beta[l * 256 + c] - mean * sc;
}

// h = out * scale + shift  (final layer only)
__global__ __launch_bounds__(256)
void bn_apply_kernel(const float* __restrict__ out, const float* __restrict__ scsh,
                     float* __restrict__ h, int total4)
{
    int i = blockIdx.x * 256 + threadIdx.x;
    if (i >= total4) return;
    int cg = i & 63;
    f32x4 sc = ((const f32x4*)scsh)[cg];
    f32x4 sh = ((const f32x4*)scsh)[64 + cg];
    f32x4 v = ((const f32x4*)out)[i];
    ((f32x4*)h)[i] = v * sc + sh;
}

extern "C" void kernel_launch(void* const* d_in, const int* in_sizes, int n_in,
                              void* d_out, int out_size, void* d_ws, size_t ws_size,
                              hipStream_t stream)
{
    const float* x     = (const float*)d_in[0];
    const int*   ei    = (const int*)d_in[1];
    const int*   ea    = (const int*)d_in[2];
    const float* Wl    = (const float*)d_in[3];
    const float* bl    = (const float*)d_in[4];
    const float* W1    = (const float*)d_in[5];
    const float* b1    = (const float*)d_in[6];
    const float* W2    = (const float*)d_in[7];
    const float* b2    = (const float*)d_in[8];
    const float* E1    = (const float*)d_in[9];
    const float* E2    = (const float*)d_in[10];
    const float* gamma = (const float*)d_in[11];
    const float* beta  = (const float*)d_in[12];

    const int N = in_sizes[0] / 128;
    const int E = in_sizes[1] / 2;

    // d_out space doubles as the bf16 agg buffer; final bn_apply overwrites it.
    __bf16* aggb = (__bf16*)d_out;               // N x 256 bf16
    float*  hfin = (float*)d_out;                // final output view

    // workspace layout
    float*  out  = (float*)d_ws;                     // N x 256 fp32
    __bf16* WlT  = (__bf16*)(out + (size_t)N * 256); // 256 x 128
    __bf16* W1T  = WlT + 256 * 128;                  // 5 x 512 x 256
    __bf16* W2T  = W1T + 5 * 512 * 256;              // 5 x 256 x 512
    float*  tab  = (float*)(W2T + 5 * 256 * 512);    // 9 x 256
    float*  selfemb = tab + 9 * 256;                 // 256
    float*  sums = selfemb + 256;                    // 512
    float*  scsh = sums + 512;                       // 512
    int*    counts = (int*)(scsh + 512);             // N
    int*    partial = counts + N;                    // N
    int*    rowptr  = partial + N;                   // N+1
    int*    woff    = rowptr + N + 1;                // N
    int*    sorted  = woff + N;                      // E
    int*    blocksums = sorted + E;                  // <=1024

    const int NB = (N + 255) / 256;
    const int EB = (E + 255) / 256;

    // --- edge sort by dst (edges constant across layers) ---
    zero_counts_kernel<<<NB, 256, 0, stream>>>(counts, N);
    hist_kernel<<<EB, 256, 0, stream>>>(ei, counts, E);
    scan1_kernel<<<NB, 256, 0, stream>>>(counts, partial, blocksums, N);
    scan2_kernel<<<1, 1024, 0, stream>>>(blocksums, NB);
    scan3_kernel<<<NB, 256, 0, stream>>>(partial, blocksums, rowptr, woff, N, E);
    scatter_sort_kernel<<<EB, 256, 0, stream>>>(ei, ea, woff, sorted, E);

    // --- weight conversion (transposed bf16) ---
    convert_wt_kernel<<<(128 * 256 + 255) / 256, 256, 0, stream>>>(Wl, WlT, 128, 256, 128 * 256);
    convert_wt_kernel<<<(5 * 256 * 512 + 255) / 256, 256, 0, stream>>>(W1, W1T, 256, 512, 5 * 256 * 512);
    convert_wt_kernel<<<(5 * 512 * 256 + 255) / 256, 256, 0, stream>>>(W2, W2T, 512, 256, 5 * 512 * 256);

    const int mtiles128 = (N + 127) / 128;
    const int mtiles64  = (N + 63) / 64;
    const int total4 = N * 64;
    const int ew_blocks = (total4 + 255) / 256;
    const int gb = (N + 3) / 4;

    // out = relu(x @ Wl + bl)
    gemm0_kernel<<<dim3(2, mtiles128), 256, 0, stream>>>(x, WlT, bl, out, N, 128, 256);

    for (int l = 0; l < 5; ++l) {
        build_table_kernel<<<10, 256, 0, stream>>>(E1, E2, l, tab, selfemb, sums);
        if (l == 0)
            gather_kernel<0><<<gb, 256, 0, stream>>>(out, rowptr, sorted, tab, selfemb,
                                                     scsh, aggb, N);
        else
            gather_kernel<1><<<gb, 256, 0, stream>>>(out, rowptr, sorted, tab, selfemb,
                                                     scsh, aggb, N);
        fused_mlp_kernel<<<mtiles64, 256, 0, stream>>>(
            aggb, W1T + (size_t)l * 512 * 256, b1 + l * 512,
            W2T + (size_t)l * 256 * 512, b2 + l * 256, out, sums, N);
        bn_finalize_kernel<<<1, 256, 0, stream>>>(sums, gamma, beta, l, N, scsh);
    }
    // final h = bn(out) -> d_out (fp32)
    bn_apply_kernel<<<ew_blocks, 256, 0, stream>>>(out, scsh, hfin, total4);
}